// Round 1
// baseline (3052.500 us; speedup 1.0000x reference)
//
#include <hip/hip_runtime.h>
#include <math.h>

// ScaleAdaptiveRouter on MI355X (gfx950)
// T=16384 tokens, H=2048, E=64 experts, SE=64, K=2112, top-2 routing.
// Strategy: fp32 VALU GEMM (no fp32 MFMA on CDNA4; bf16 MFMA would flip
// top-k selections). lane==expert; softmax denominator cancels in the
// top-2 renormalization so only top-2 logits are needed.

#define H_DIM 2048
#define K_TOTAL 2112
#define E_DIM 64
#define SE_DIM 64
#define TOKENS_PER_BLOCK 32
#define TOK_PER_WAVE 8
#define BK 64
#define NKB (H_DIM / BK)     // 32 K-chunks over the x part
#define WS_STRIDE 65         // +1 pad: kills 16-way LDS write conflict on W transpose
#define NBLOCKS 512          // 16384 / 32

__launch_bounds__(256, 2)
__global__ void ScaleAdaptiveRouter_kernel(const float* __restrict__ x,
                                           const float* __restrict__ se,
                                           const float* __restrict__ W,
                                           const float* __restrict__ noise,
                                           const int* __restrict__ sidx,
                                           float* __restrict__ out) {
    // double-buffered LDS: x tile [32 tok][64 k], W tile transposed [64 k][64 e] (pad 65)
    __shared__ __align__(16) float xs[2][TOKENS_PER_BLOCK * BK];   // 2 x 8 KB
    __shared__ __align__(16) float ws[2][BK * WS_STRIDE];          // 2 x 16.25 KB

    const int tid  = threadIdx.x;
    const int lane = tid & 63;        // == expert index
    const int wave = tid >> 6;        // 0..3
    const int tok_base = blockIdx.x * TOKENS_PER_BLOCK;
    const int wtok = wave * TOK_PER_WAVE;   // this wave's first token within block

    // ---- per-expert tail constant: emb . W[e, 2048:2112] (once per block) ----
    const float* emb = se + (*sidx) * SE_DIM;
    float tail = 0.0f;
    #pragma unroll
    for (int j = 0; j < SE_DIM; ++j)
        tail = fmaf(emb[j], W[(size_t)lane * K_TOTAL + H_DIM + j], tail);

    float acc[TOK_PER_WAVE];
    #pragma unroll
    for (int t = 0; t < TOK_PER_WAVE; ++t) acc[t] = tail;

    // ---- prefetch registers for global->LDS staging ----
    float4 xr[2];   // 512 float4 of x-tile / 256 threads
    float4 wr[4];   // 1024 float4 of W-tile / 256 threads

    auto load_tile = [&](int kb) {
        const int k0 = kb * BK;
        #pragma unroll
        for (int i = 0; i < 2; ++i) {
            int j = tid + i * 256;            // 0..511
            int row = j >> 4, c4 = j & 15;    // row: token in tile, c4: float4 col
            xr[i] = *(const float4*)(x + (size_t)(tok_base + row) * H_DIM + k0 + c4 * 4);
        }
        #pragma unroll
        for (int i = 0; i < 4; ++i) {
            int j = tid + i * 256;            // 0..1023
            int e = j >> 4, c4 = j & 15;
            wr[i] = *(const float4*)(W + (size_t)e * K_TOTAL + k0 + c4 * 4);
        }
    };
    auto store_tile = [&](int buf) {
        #pragma unroll
        for (int i = 0; i < 2; ++i) {
            int j = tid + i * 256;
            int row = j >> 4, c4 = j & 15;
            *(float4*)&xs[buf][row * BK + c4 * 4] = xr[i];
        }
        #pragma unroll
        for (int i = 0; i < 4; ++i) {
            int j = tid + i * 256;
            int e = j >> 4, c4 = j & 15;
            // transpose into [k][e]; stride 65 -> write banks (4*c4+m+e/?) spread, 2-way max
            ws[buf][(c4 * 4 + 0) * WS_STRIDE + e] = wr[i].x;
            ws[buf][(c4 * 4 + 1) * WS_STRIDE + e] = wr[i].y;
            ws[buf][(c4 * 4 + 2) * WS_STRIDE + e] = wr[i].z;
            ws[buf][(c4 * 4 + 3) * WS_STRIDE + e] = wr[i].w;
        }
    };

    load_tile(0);
    store_tile(0);
    __syncthreads();

    // ---- main K loop over x columns, LDS double-buffered, 1 barrier/iter ----
    for (int kb = 0; kb < NKB; ++kb) {
        if (kb + 1 < NKB) load_tile(kb + 1);          // global loads issue early
        const float* xb = xs[kb & 1];
        const float* wb = ws[kb & 1];
        #pragma unroll
        for (int k4 = 0; k4 < BK; k4 += 4) {
            // per-lane W for its expert: banks e%32 -> 2-way aliasing (free)
            float w0 = wb[(k4 + 0) * WS_STRIDE + lane];
            float w1 = wb[(k4 + 1) * WS_STRIDE + lane];
            float w2 = wb[(k4 + 2) * WS_STRIDE + lane];
            float w3 = wb[(k4 + 3) * WS_STRIDE + lane];
            #pragma unroll
            for (int t = 0; t < TOK_PER_WAVE; ++t) {
                // wave-uniform address -> LDS broadcast read, no conflicts
                float4 xv = *(const float4*)&xb[(wtok + t) * BK + k4];
                acc[t] = fmaf(xv.x, w0, acc[t]);
                acc[t] = fmaf(xv.y, w1, acc[t]);
                acc[t] = fmaf(xv.z, w2, acc[t]);
                acc[t] = fmaf(xv.w, w3, acc[t]);
            }
        }
        if (kb + 1 < NKB) {
            store_tile((kb + 1) & 1);   // target buffer's readers finished before prev barrier
            __syncthreads();
        }
    }

    // ---- epilogue: noise, top-2 over lanes, renormalize, scatter ----
    #pragma unroll
    for (int t = 0; t < TOK_PER_WAVE; ++t) {
        const size_t g = (size_t)(tok_base + wtok + t);
        float logit = fmaf(noise[g * E_DIM + lane], 0.1f, acc[t]);

        // top-1 (value, lowest index on ties -> matches lax.top_k stability)
        float v1 = logit; int i1 = lane;
        #pragma unroll
        for (int off = 32; off; off >>= 1) {
            float ov = __shfl_xor(v1, off, 64);
            int   oi = __shfl_xor(i1, off, 64);
            if (ov > v1 || (ov == v1 && oi < i1)) { v1 = ov; i1 = oi; }
        }
        // top-2: exclude i1
        float v2 = (lane == i1) ? -__builtin_inff() : logit;
        int   i2 = lane;
        #pragma unroll
        for (int off = 32; off; off >>= 1) {
            float ov = __shfl_xor(v2, off, 64);
            int   oi = __shfl_xor(i2, off, 64);
            if (ov > v2 || (ov == v2 && oi < i2)) { v2 = ov; i2 = oi; }
        }

        // softmax denom cancels: w1 = 1/(1+e^{l2-l1}), w2 = 1 - w1
        float d   = expf(v2 - v1);          // <= 1, no overflow
        float rw1 = 1.0f / (1.0f + d);
        float rw2 = d / (1.0f + d);
        float o = (lane == i1) ? rw1 : ((lane == i2) ? rw2 : 0.0f);
        out[g * E_DIM + lane] = o;          // coalesced 256B row store
    }
}

extern "C" void kernel_launch(void* const* d_in, const int* in_sizes, int n_in,
                              void* d_out, int out_size, void* d_ws, size_t ws_size,
                              hipStream_t stream) {
    const float* x     = (const float*)d_in[0];
    const float* se    = (const float*)d_in[1];
    const float* W     = (const float*)d_in[2];
    const float* noise = (const float*)d_in[3];
    const int*   sidx  = (const int*)d_in[4];
    float* out = (float*)d_out;

    hipLaunchKernelGGL(ScaleAdaptiveRouter_kernel, dim3(NBLOCKS), dim3(256), 0, stream,
                       x, se, W, noise, sidx, out);
}

// Round 2
// 396.767 us; speedup vs baseline: 7.6934x; 7.6934x over previous
//
#include <hip/hip_runtime.h>
#include <math.h>

// ScaleAdaptiveRouter on MI355X (gfx950)
// T=16384 tokens, H=2048, E=64 experts, SE=64, K=2112, top-2 routing.
//
// Round-2 design: LDS-free, lambda-free (R1's lambda-captured staging
// arrays went to scratch -> 9.5 GB of HBM traffic, 2.7 ms).
//   lane == expert (64 lanes = 64 experts).
//   x[token][k] is wave-uniform  -> scalar/broadcast global loads.
//   W[lane][k]  is per-lane f4   -> L2-resident after first touch (540 KB).
//   Softmax denominator cancels in top-2 renorm: only top-2 logits needed.
//   fp32 VALU GEMM (no fp32 MFMA on CDNA4; bf16 would flip top-k picks).

#define H_DIM 2048
#define K_TOTAL 2112
#define E_DIM 64
#define SE_DIM 64
#define T_PER_WAVE 8
#define N_WAVES 4
#define T_PER_BLOCK (T_PER_WAVE * N_WAVES)   // 32
#define NBLOCKS (16384 / T_PER_BLOCK)        // 512 -> 2 blocks/CU, 8 waves/CU

__launch_bounds__(256, 4)
__global__ void ScaleAdaptiveRouter_kernel(const float* __restrict__ x,
                                           const float* __restrict__ se,
                                           const float* __restrict__ W,
                                           const float* __restrict__ noise,
                                           const int* __restrict__ sidx,
                                           float* __restrict__ out) {
    const int tid  = threadIdx.x;
    const int lane = tid & 63;                                    // expert index
    const int wave = __builtin_amdgcn_readfirstlane(tid >> 6);    // force wave-uniform
    const int tok0 = blockIdx.x * T_PER_BLOCK + wave * T_PER_WAVE;

    const float* wrow = W + (size_t)lane * K_TOTAL;   // this lane's expert row
    const float* xr0  = x + (size_t)tok0 * H_DIM;     // wave-uniform base

    // ---- per-expert tail constant: emb . W[e, 2048:2112] ----
    const float* emb = se + (*sidx) * SE_DIM;
    float tail = 0.0f;
    #pragma unroll
    for (int j = 0; j < SE_DIM; j += 4) {
        float4 e4 = *(const float4*)(emb + j);          // uniform
        float4 w4 = *(const float4*)(wrow + H_DIM + j); // per-lane
        tail = fmaf(e4.x, w4.x, tail);
        tail = fmaf(e4.y, w4.y, tail);
        tail = fmaf(e4.z, w4.z, tail);
        tail = fmaf(e4.w, w4.w, tail);
    }

    float acc[T_PER_WAVE];
    #pragma unroll
    for (int t = 0; t < T_PER_WAVE; ++t) acc[t] = tail;

    // ---- main K loop: per-lane W float4 (L2) x wave-uniform x float4 ----
    // 8 independent acc chains/lane -> FMA latency (4cyc) hidden at 2cyc issue.
    #pragma unroll 2
    for (int k = 0; k < H_DIM; k += 4) {
        float4 w4 = *(const float4*)(wrow + k);
        #pragma unroll
        for (int t = 0; t < T_PER_WAVE; ++t) {
            float4 xv = *(const float4*)(xr0 + (size_t)t * H_DIM + k);  // uniform addr
            acc[t] = fmaf(xv.x, w4.x, acc[t]);
            acc[t] = fmaf(xv.y, w4.y, acc[t]);
            acc[t] = fmaf(xv.z, w4.z, acc[t]);
            acc[t] = fmaf(xv.w, w4.w, acc[t]);
        }
    }

    // ---- epilogue: noise, top-2 over lanes, renormalize, scatter ----
    #pragma unroll
    for (int t = 0; t < T_PER_WAVE; ++t) {
        const size_t g = (size_t)(tok0 + t);
        float logit = fmaf(noise[g * E_DIM + lane], 0.1f, acc[t]);

        // top-1 (max value, lowest index on ties -> matches lax.top_k)
        float v1 = logit; int i1 = lane;
        #pragma unroll
        for (int off = 32; off; off >>= 1) {
            float ov = __shfl_xor(v1, off, 64);
            int   oi = __shfl_xor(i1, off, 64);
            if (ov > v1 || (ov == v1 && oi < i1)) { v1 = ov; i1 = oi; }
        }
        // top-2: exclude i1
        float v2 = (lane == i1) ? -__builtin_inff() : logit;
        int   i2 = lane;
        #pragma unroll
        for (int off = 32; off; off >>= 1) {
            float ov = __shfl_xor(v2, off, 64);
            int   oi = __shfl_xor(i2, off, 64);
            if (ov > v2 || (ov == v2 && oi < i2)) { v2 = ov; i2 = oi; }
        }

        // full softmax denom cancels: w1 = 1/(1+e^{l2-l1}), w2 = 1-w1
        float d   = expf(v2 - v1);               // <= 1, no overflow
        float inv = 1.0f / (1.0f + d);
        float o = (lane == i1) ? inv : ((lane == i2) ? d * inv : 0.0f);
        out[g * E_DIM + lane] = o;               // coalesced 256B row store
    }
}

extern "C" void kernel_launch(void* const* d_in, const int* in_sizes, int n_in,
                              void* d_out, int out_size, void* d_ws, size_t ws_size,
                              hipStream_t stream) {
    const float* x     = (const float*)d_in[0];
    const float* se    = (const float*)d_in[1];
    const float* W     = (const float*)d_in[2];
    const float* noise = (const float*)d_in[3];
    const int*   sidx  = (const int*)d_in[4];
    float* out = (float*)d_out;

    hipLaunchKernelGGL(ScaleAdaptiveRouter_kernel, dim3(NBLOCKS), dim3(256), 0, stream,
                       x, se, W, noise, sidx, out);
}

// Round 3
// 309.354 us; speedup vs baseline: 9.8673x; 1.2826x over previous
//
#include <hip/hip_runtime.h>
#include <math.h>
#include <stdint.h>

// ScaleAdaptiveRouter on MI355X (gfx950) — Round 3
// T=16384 tokens, H=2048, E=64 experts, K=2112, top-2 routing.
//
// R2 was latency-bound (VALUBusy 13%, HBM 7%): loop-carried x loads exposed
// ~900cyc HBM latency, and W[lane][k] per-lane loads touched 64 cachelines
// per instruction. R3:
//   * x staged into double-buffered LDS via global_load_lds (1KB/instr,
//     whole tile in flight, 1 barrier/tile) -> latency hidden under compute.
//   * W re-packed by a prep kernel into W2[k4][e] (float4) in d_ws ->
//     per-lane W loads become fully coalesced and L1-resident.
//   * lane == expert; x read from LDS as wave-uniform b128 broadcasts.
//   * top-2 renorm: softmax denominator cancels, only top-2 logits needed.

#define H_DIM 2048
#define K_TOTAL 2112
#define E_DIM 64
#define SE_DIM 64
#define BK 64
#define NKB (H_DIM / BK)          // 32 x-tiles
#define T_PER_WAVE 8
#define T_PER_BLOCK 32            // 4 waves x 8 tokens
#define NBLOCKS (16384 / T_PER_BLOCK)   // 512 -> 2 blocks/CU
#define NK4 (K_TOTAL / 4)         // 528 float4-chunks per expert row

typedef uint32_t __attribute__((address_space(1))) gu32_t;
typedef uint32_t __attribute__((address_space(3))) lu32_t;

__device__ __forceinline__ void gload_lds16(const float* g, float* l) {
    __builtin_amdgcn_global_load_lds((const gu32_t*)g, (lu32_t*)l, 16, 0, 0);
}

// ---- prep: W2[k4*64 + e] = float4(W[e][4k4 .. 4k4+3]), k4 in [0,528) ----
__global__ void pack_w_kernel(const float* __restrict__ W, float4* __restrict__ W2) {
    int tid = blockIdx.x * 256 + threadIdx.x;      // 0 .. 33791
    int e  = tid / NK4;
    int k4 = tid - e * NK4;
    float4 v = *(const float4*)(W + (size_t)e * K_TOTAL + 4 * k4);  // coalesced read
    W2[(size_t)k4 * E_DIM + e] = v;                                  // scattered write (540KB, trivial)
}

__launch_bounds__(256, 2)
__global__ void ScaleAdaptiveRouter_kernel(const float* __restrict__ x,
                                           const float* __restrict__ se,
                                           const float4* __restrict__ W2,
                                           const float* __restrict__ noise,
                                           const int* __restrict__ sidx,
                                           float* __restrict__ out) {
    __shared__ __align__(16) float xs[2][T_PER_BLOCK * BK];   // 2 x 8 KB, no padding (global_load_lds)

    const int tid  = threadIdx.x;
    const int lane = tid & 63;                                  // expert index
    const int wave = __builtin_amdgcn_readfirstlane(tid >> 6);
    const int tok0blk = blockIdx.x * T_PER_BLOCK;
    const int wtok = wave * T_PER_WAVE;

    // ---- issue x tile 0 immediately (latency overlapped with tail compute) ----
    {
        const float* gsrc = x + (size_t)tok0blk * H_DIM;        // kb = 0
        #pragma unroll
        for (int c = 0; c < 2; ++c) {
            int f = tid + c * 256;                               // float4 index in tile
            int row = f >> 4, c4 = f & 15;
            gload_lds16(gsrc + (size_t)row * H_DIM + c4 * 4, &xs[0][f * 4]);
        }
    }

    // ---- tail constant: emb . W[e, 2048:2112] via W2 rows 512..527 (coalesced) ----
    const float* emb = se + (*sidx) * SE_DIM;
    float tail = 0.0f;
    #pragma unroll
    for (int j4 = 0; j4 < SE_DIM / 4; ++j4) {
        float4 e4 = *(const float4*)(emb + 4 * j4);              // uniform
        float4 w4 = W2[(size_t)(512 + j4) * E_DIM + lane];       // coalesced
        tail = fmaf(e4.x, w4.x, tail);
        tail = fmaf(e4.y, w4.y, tail);
        tail = fmaf(e4.z, w4.z, tail);
        tail = fmaf(e4.w, w4.w, tail);
    }

    float acc[T_PER_WAVE];
    #pragma unroll
    for (int t = 0; t < T_PER_WAVE; ++t) acc[t] = tail;

    // ---- main loop: 32 tiles of BK=64, LDS double-buffered, 1 barrier/tile ----
    for (int kb = 0; kb < NKB; ++kb) {
        __syncthreads();    // drains tile-kb loads (vmcnt) + guards buffer reuse
        if (kb + 1 < NKB) { // issue tile kb+1 while computing tile kb
            const float* gsrc = x + (size_t)tok0blk * H_DIM + (kb + 1) * BK;
            int buf = (kb + 1) & 1;
            #pragma unroll
            for (int c = 0; c < 2; ++c) {
                int f = tid + c * 256;
                int row = f >> 4, c4 = f & 15;
                gload_lds16(gsrc + (size_t)row * H_DIM + c4 * 4, &xs[buf][f * 4]);
            }
        }
        const float*  xb  = xs[kb & 1] + wtok * BK;              // wave-uniform base
        const float4* w2k = W2 + (size_t)kb * (BK / 4) * E_DIM + lane;
        #pragma unroll 2
        for (int k4 = 0; k4 < BK / 4; ++k4) {
            float4 w4 = w2k[(size_t)k4 * E_DIM];                 // coalesced, L1-resident
            #pragma unroll
            for (int t = 0; t < T_PER_WAVE; ++t) {
                float4 xv = *(const float4*)(xb + t * BK + k4 * 4);  // uniform b128 broadcast
                acc[t] = fmaf(xv.x, w4.x, acc[t]);
                acc[t] = fmaf(xv.y, w4.y, acc[t]);
                acc[t] = fmaf(xv.z, w4.z, acc[t]);
                acc[t] = fmaf(xv.w, w4.w, acc[t]);
            }
        }
    }

    // ---- epilogue: noise, top-2 over lanes, renormalize, scatter ----
    #pragma unroll
    for (int t = 0; t < T_PER_WAVE; ++t) {
        const size_t g = (size_t)(tok0blk + wtok + t);
        float logit = fmaf(noise[g * E_DIM + lane], 0.1f, acc[t]);

        float v1 = logit; int i1 = lane;
        #pragma unroll
        for (int off = 32; off; off >>= 1) {
            float ov = __shfl_xor(v1, off, 64);
            int   oi = __shfl_xor(i1, off, 64);
            if (ov > v1 || (ov == v1 && oi < i1)) { v1 = ov; i1 = oi; }
        }
        float v2 = (lane == i1) ? -__builtin_inff() : logit;
        int   i2 = lane;
        #pragma unroll
        for (int off = 32; off; off >>= 1) {
            float ov = __shfl_xor(v2, off, 64);
            int   oi = __shfl_xor(i2, off, 64);
            if (ov > v2 || (ov == v2 && oi < i2)) { v2 = ov; i2 = oi; }
        }

        float d   = expf(v2 - v1);               // <= 1
        float inv = 1.0f / (1.0f + d);
        float o = (lane == i1) ? inv : ((lane == i2) ? d * inv : 0.0f);
        out[g * E_DIM + lane] = o;               // coalesced row store
    }
}

extern "C" void kernel_launch(void* const* d_in, const int* in_sizes, int n_in,
                              void* d_out, int out_size, void* d_ws, size_t ws_size,
                              hipStream_t stream) {
    const float* x     = (const float*)d_in[0];
    const float* se    = (const float*)d_in[1];
    const float* W     = (const float*)d_in[2];
    const float* noise = (const float*)d_in[3];
    const int*   sidx  = (const int*)d_in[4];
    float* out = (float*)d_out;
    float4* W2 = (float4*)d_ws;    // 528 * 64 * 16 B = 540672 B

    // pack W -> W2 (stream-ordered before the router kernel)
    hipLaunchKernelGGL(pack_w_kernel, dim3((E_DIM * NK4) / 256), dim3(256), 0, stream, W, W2);
    hipLaunchKernelGGL(ScaleAdaptiveRouter_kernel, dim3(NBLOCKS), dim3(256), 0, stream,
                       x, se, W2, noise, sidx, out);
}